// Round 1
// 1090.864 us; speedup vs baseline: 1.0213x; 1.0213x over previous
//
#include <hip/hip_runtime.h>
#include <hip/hip_bf16.h>

#define T_TOKENS 16384
#define DM 1024
#define DFF 4096
#define NEXP 8

#define BM 128
#define BN 128
#define BKS 32
#define NTILES 136

typedef unsigned short ushort_t;
typedef __attribute__((ext_vector_type(8))) __bf16 bf16x8;
typedef __attribute__((ext_vector_type(4))) float f32x4;

__device__ __forceinline__ void async16(void* lds, const void* g) {
  __builtin_amdgcn_global_load_lds(
      (__attribute__((address_space(1))) void*)(void*)g,
      (__attribute__((address_space(3))) void*)lds, 16, 0, 0);
}

__device__ __forceinline__ ushort_t f2bf(float f) {
  union { float f; unsigned u; } v;
  v.f = f;
  unsigned r = v.u + 0x7FFF + ((v.u >> 16) & 1);
  return (ushort_t)(r >> 16);
}

// ---------------- router: one wave per token ----------------
__global__ __launch_bounds__(256) void router_kernel(
    const float* __restrict__ x, const float* __restrict__ Wr,
    const float* __restrict__ br, int* __restrict__ eidx,
    float* __restrict__ wgt, int* __restrict__ count) {
  int wave = threadIdx.x >> 6;
  int lane = threadIdx.x & 63;
  int t = blockIdx.x * 4 + wave;
  if (t >= T_TOKENS) return;

  float acc[8];
#pragma unroll
  for (int e = 0; e < 8; e++) acc[e] = 0.f;

  const float* xr = x + (size_t)t * DM;
  for (int k = lane; k < DM; k += 64) {
    float xv = xr[k];
    const float4* w4 = (const float4*)(Wr + (size_t)k * 8);
    float4 w0 = w4[0];
    float4 w1 = w4[1];
    acc[0] += xv * w0.x; acc[1] += xv * w0.y;
    acc[2] += xv * w0.z; acc[3] += xv * w0.w;
    acc[4] += xv * w1.x; acc[5] += xv * w1.y;
    acc[6] += xv * w1.z; acc[7] += xv * w1.w;
  }
#pragma unroll
  for (int e = 0; e < 8; e++) {
#pragma unroll
    for (int m = 32; m > 0; m >>= 1) acc[e] += __shfl_xor(acc[e], m, 64);
  }
  if (lane == 0) {
    float lg[8];
    float mx = -1e30f;
#pragma unroll
    for (int e = 0; e < 8; e++) {
      lg[e] = acc[e] + br[e];
      mx = fmaxf(mx, lg[e]);
    }
    float s = 0.f;
#pragma unroll
    for (int e = 0; e < 8; e++) s += expf(lg[e] - mx);
    int am = 0;
    float best = lg[0];
#pragma unroll
    for (int e = 1; e < 8; e++) {
      if (lg[e] > best) { best = lg[e]; am = e; }
    }
    eidx[t] = am;
    wgt[t] = expf(best - mx) / s;
    atomicAdd(&count[am], 1);
  }
}

// ---------------- scan + dense tile table ----------------
__global__ void scan_kernel(const int* __restrict__ count, int* __restrict__ offsets,
                            int* __restrict__ cursor, int4* __restrict__ tiles) {
  if (threadIdx.x == 0) {
    int run = 0;
    for (int e = 0; e < NEXP; e++) {
      offsets[e] = run;
      cursor[e] = run;
      run += count[e];
    }
    offsets[NEXP] = run;
    int nt = 0;
    for (int e = 0; e < NEXP; e++) {
      int beg = offsets[e];
      int rows = offsets[e + 1] - beg;
      for (int r0 = 0; r0 < rows; r0 += BM) {
        tiles[nt] = make_int4(e, beg, rows, r0);
        nt++;
      }
    }
    for (; nt < NTILES; nt++) tiles[nt] = make_int4(-1, 0, 0, 0);
  }
}

// ---------------- scatter token ids into per-expert lists ----------------
__global__ __launch_bounds__(256) void scatter_kernel(
    const int* __restrict__ eidx, int* __restrict__ cursor, int* __restrict__ perm) {
  int t = blockIdx.x * 256 + threadIdx.x;
  if (t < T_TOKENS) {
    int e = eidx[t];
    int pos = atomicAdd(&cursor[e], 1);
    perm[pos] = t;
  }
}

// ---------------- gather x rows into expert order, fp32 -> bf16 ----------------
__global__ __launch_bounds__(256) void gather_x_kernel(
    const float* __restrict__ x, const int* __restrict__ perm,
    ushort_t* __restrict__ xg) {
  int g = blockIdx.x;
  int tok = perm[g];
  int tid = threadIdx.x;
  float4 v = ((const float4*)(x + (size_t)tok * DM))[tid];
  ushort4 o;
  o.x = f2bf(v.x); o.y = f2bf(v.y); o.z = f2bf(v.z); o.w = f2bf(v.w);
  ((ushort4*)(xg + (size_t)g * DM))[tid] = o;
}

// ---------------- transpose+convert: W [E][R][C] fp32 -> WT [E][C][R] bf16 ----------------
__global__ __launch_bounds__(256) void convT_kernel(
    const float* __restrict__ W, ushort_t* __restrict__ WT, int R, int C) {
  __shared__ float t[64][65];
  int e = blockIdx.z;
  int r0 = blockIdx.y << 6, c0 = blockIdx.x << 6;
  int tid = threadIdx.x;
  const float* Wp = W + (size_t)e * R * C;
#pragma unroll
  for (int i = 0; i < 4; i++) {
    int r = (tid >> 4) + i * 16;
    int c = (tid & 15) * 4;
    float4 v = *(const float4*)(Wp + (size_t)(r0 + r) * C + c0 + c);
    t[r][c] = v.x; t[r][c + 1] = v.y; t[r][c + 2] = v.z; t[r][c + 3] = v.w;
  }
  __syncthreads();
  ushort_t* Op = WT + (size_t)e * R * C;
#pragma unroll
  for (int i = 0; i < 4; i++) {
    int c = (tid >> 4) + i * 16;
    int r = (tid & 15) * 4;
    ushort4 o;
    o.x = f2bf(t[r][c]);
    o.y = f2bf(t[r + 1][c]);
    o.z = f2bf(t[r + 2][c]);
    o.w = f2bf(t[r + 3][c]);
    *(ushort4*)(Op + (size_t)(c0 + c) * R + r0 + r) = o;
  }
}

// stage one BMxBKS A-tile and BNxBKS B-tile into LDS (512 lanes x 16B x 2).
// A rows are clamped to rmax (garbage rows masked at epilogue) so no padded
// token-dim allocation is needed.
template <int LDA, int LDB>
__device__ __forceinline__ void stage_tile(
    ushort_t* As, ushort_t* Bs,
    const ushort_t* Ap, const ushort_t* Bp,
    int k0, int tid, int rmax) {
#pragma unroll
  for (int it = 0; it < 2; it++) {
    int idx = it * 256 + tid;
    int rr = idx >> 2;
    int pp = (idx & 3) * 8;
    int rc = rr > rmax ? rmax : rr;
    async16(As + idx * 8, Ap + (size_t)rc * LDA + k0 + pp);
    async16(Bs + idx * 8, Bp + (size_t)rr * LDB + k0 + pp);
  }
}

// bijective XCD-chunk swizzle (m204). nwg % 8 == 0 for both GEMM grids,
// but use the general form anyway.
__device__ __forceinline__ int xcd_swizzle(int flat, int nwg) {
  int q = nwg >> 3, r = nwg & 7;
  int xcd = flat & 7, loc = flat >> 3;
  return (xcd < r ? xcd * (q + 1) : r * (q + 1) + (xcd - r) * q) + loc;
}

// ---------------- MFMA GEMM1: h = relu(Xg @ W1 + b1), full DFF ----------------
__global__ __launch_bounds__(256) void gemm1_kernel(
    const ushort_t* __restrict__ xg, const ushort_t* __restrict__ W1T,
    const float* __restrict__ b1, const int4* __restrict__ tiles,
    ushort_t* __restrict__ h) {
  const int NCOL = DFF / BN;  // 32
  int flat = blockIdx.y * NCOL + blockIdx.x;
  int wgid = xcd_swizzle(flat, NCOL * NTILES);
  int ty = wgid / NCOL;
  int cx = wgid - ty * NCOL;

  int4 tl = tiles[ty];
  if (tl.x < 0) return;
  int e = tl.x, beg = tl.y, rows = tl.z, row0 = tl.w;
  int col0 = cx * BN;
  int rmax = rows - row0 - 1;  // >= 0 by construction

  __shared__ ushort_t As[2][BM * BKS];
  __shared__ ushort_t Bs[2][BN * BKS];

  int tid = threadIdx.x;
  int wave = tid >> 6, lane = tid & 63;
  int wm = (wave & 1) * 64, wn = (wave >> 1) * 64;
  int lr = lane & 15;
  int kf = (lane >> 4) * 8;

  f32x4 acc[4][4] = {};

  const ushort_t* Ap = xg + (size_t)(beg + row0) * DM;
  const ushort_t* Bp = W1T + ((size_t)e * DFF + col0) * DM;

  stage_tile<DM, DM>(As[0], Bs[0], Ap, Bp, 0, tid, rmax);
  __syncthreads();

  int cur = 0;
  const int KT = DM / BKS;  // 32
  for (int t = 0; t < KT; t++) {
    if (t + 1 < KT)
      stage_tile<DM, DM>(As[cur ^ 1], Bs[cur ^ 1], Ap, Bp, (t + 1) * BKS, tid, rmax);
    bf16x8 af[4], bfr[4];
#pragma unroll
    for (int i = 0; i < 4; i++)
      af[i] = *(const bf16x8*)(&As[cur][(wm + i * 16 + lr) * BKS + kf]);
#pragma unroll
    for (int j = 0; j < 4; j++)
      bfr[j] = *(const bf16x8*)(&Bs[cur][(wn + j * 16 + lr) * BKS + kf]);
#pragma unroll
    for (int i = 0; i < 4; i++)
#pragma unroll
      for (int j = 0; j < 4; j++)
        acc[i][j] = __builtin_amdgcn_mfma_f32_16x16x32_bf16(af[i], bfr[j], acc[i][j], 0, 0, 0);
    __syncthreads();  // drains this iter's prefetch (vmcnt 0) + lgkm
    cur ^= 1;
  }

  int rquad = (lane >> 4) * 4;
#pragma unroll
  for (int i = 0; i < 4; i++) {
    int mb = wm + i * 16 + rquad;
#pragma unroll
    for (int r = 0; r < 4; r++) {
      int m = mb + r;
      if (row0 + m < rows) {
        size_t hrow = (size_t)(beg + row0 + m) * DFF;
#pragma unroll
        for (int j = 0; j < 4; j++) {
          int c = col0 + wn + j * 16 + lr;
          float v = acc[i][j][r] + b1[(size_t)e * DFF + c];
          h[hrow + c] = f2bf(fmaxf(v, 0.f));
        }
      }
    }
  }
}

// ---------------- MFMA GEMM2: out = (H @ W2 + b2) * w, full K=DFF ----------------
__global__ __launch_bounds__(256) void gemm2_kernel(
    const ushort_t* __restrict__ h, const ushort_t* __restrict__ W2T,
    const float* __restrict__ b2, const int4* __restrict__ tiles,
    const int* __restrict__ perm, const float* __restrict__ wgt,
    float* __restrict__ out) {
  const int NCOL = DM / BN;  // 8
  int flat = blockIdx.y * NCOL + blockIdx.x;
  int wgid = xcd_swizzle(flat, NCOL * NTILES);
  int ty = wgid / NCOL;
  int cx = wgid - ty * NCOL;

  int4 tl = tiles[ty];
  if (tl.x < 0) return;
  int e = tl.x, beg = tl.y, rows = tl.z, row0 = tl.w;
  int col0 = cx * BN;
  int rmax = rows - row0 - 1;

  __shared__ ushort_t As[2][BM * BKS];
  __shared__ ushort_t Bs[2][BN * BKS];
  __shared__ int toks[BM];

  int tid = threadIdx.x;
  if (tid < BM) {
    int r = row0 + tid;
    toks[tid] = (r < rows) ? perm[beg + r] : 0;
  }

  int wave = tid >> 6, lane = tid & 63;
  int wm = (wave & 1) * 64, wn = (wave >> 1) * 64;
  int lr = lane & 15;
  int kf = (lane >> 4) * 8;

  f32x4 acc[4][4] = {};

  const ushort_t* Ap = h + (size_t)(beg + row0) * DFF;
  const ushort_t* Bp = W2T + ((size_t)e * DM + col0) * DFF;

  stage_tile<DFF, DFF>(As[0], Bs[0], Ap, Bp, 0, tid, rmax);
  __syncthreads();

  int cur = 0;
  const int KT = DFF / BKS;  // 128
  for (int t = 0; t < KT; t++) {
    if (t + 1 < KT)
      stage_tile<DFF, DFF>(As[cur ^ 1], Bs[cur ^ 1], Ap, Bp, (t + 1) * BKS, tid, rmax);
    bf16x8 af[4], bfr[4];
#pragma unroll
    for (int i = 0; i < 4; i++)
      af[i] = *(const bf16x8*)(&As[cur][(wm + i * 16 + lr) * BKS + kf]);
#pragma unroll
    for (int j = 0; j < 4; j++)
      bfr[j] = *(const bf16x8*)(&Bs[cur][(wn + j * 16 + lr) * BKS + kf]);
#pragma unroll
    for (int i = 0; i < 4; i++)
#pragma unroll
      for (int j = 0; j < 4; j++)
        acc[i][j] = __builtin_amdgcn_mfma_f32_16x16x32_bf16(af[i], bfr[j], acc[i][j], 0, 0, 0);
    __syncthreads();
    cur ^= 1;
  }

  int rquad = (lane >> 4) * 4;
#pragma unroll
  for (int i = 0; i < 4; i++) {
    int mb = wm + i * 16 + rquad;
#pragma unroll
    for (int r = 0; r < 4; r++) {
      int m = mb + r;
      if (row0 + m < rows) {
        int tok = toks[m];
        float* orow = out + (size_t)tok * DM;
        float w = wgt[tok];
#pragma unroll
        for (int j = 0; j < 4; j++) {
          int c = col0 + wn + j * 16 + lr;
          orow[c] = (acc[i][j][r] + b2[(size_t)e * DM + c]) * w;
        }
      }
    }
  }
}

extern "C" void kernel_launch(void* const* d_in, const int* in_sizes, int n_in,
                              void* d_out, int out_size, void* d_ws, size_t ws_size,
                              hipStream_t stream) {
  (void)in_sizes; (void)n_in; (void)out_size; (void)ws_size;
  const float* x  = (const float*)d_in[0];
  const float* Wr = (const float*)d_in[1];
  const float* br = (const float*)d_in[2];
  const float* W1 = (const float*)d_in[3];
  const float* b1 = (const float*)d_in[4];
  const float* W2 = (const float*)d_in[5];
  const float* b2 = (const float*)d_in[6];
  float* out = (float*)d_out;

  char* ws = (char*)d_ws;
  int*   eidx    = (int*)(ws + 0);
  float* wgt     = (float*)(ws + 65536);
  int*   count   = (int*)(ws + 131072);
  int*   offsets = (int*)(ws + 131136);
  int*   cursor  = (int*)(ws + 131264);
  int4*  tiles   = (int4*)(ws + 131392);   // 136 * 16 B
  int*   perm    = (int*)(ws + 135168);    // 64 KB

  // Single-slab layout via W1T/W2T sharing one buffer (convert W2 after gemm1).
  // No padded token rows (A-staging clamps instead).
  // total = 262144 + 32MB(xg) + 64MB(WT) + 128MB(h) = 235,143,168 B
  //       < 235,929,600 B proven-available watermark of the previous version.
  size_t XG_BYTES = (size_t)T_TOKENS * DM * sizeof(ushort_t);   // 33,554,432
  ushort_t* xg = (ushort_t*)(ws + 262144);
  ushort_t* WT = (ushort_t*)(ws + 262144 + XG_BYTES);           // shared W1T/W2T, 64 MB
  ushort_t* h  = (ushort_t*)(ws + 262144 + XG_BYTES + 67108864);

  hipMemsetAsync(count, 0, 32, stream);

  router_kernel<<<T_TOKENS / 4, 256, 0, stream>>>(x, Wr, br, eidx, wgt, count);
  scan_kernel<<<1, 64, 0, stream>>>(count, offsets, cursor, tiles);
  scatter_kernel<<<T_TOKENS / 256, 256, 0, stream>>>(eidx, cursor, perm);
  gather_x_kernel<<<T_TOKENS, 256, 0, stream>>>(x, perm, xg);

  // W1 -> WT, gemm1 over full DFF
  convT_kernel<<<dim3(DFF / 64, DM / 64, NEXP), 256, 0, stream>>>(W1, WT, DM, DFF);
  gemm1_kernel<<<dim3(DFF / BN, NTILES), 256, 0, stream>>>(xg, WT, b1, tiles, h);

  // W2 -> WT (same buffer, W1T dead now), gemm2 over full K=DFF
  convT_kernel<<<dim3(DM / 64, DFF / 64, NEXP), 256, 0, stream>>>(W2, WT, DFF, DM);
  gemm2_kernel<<<dim3(DM / BN, NTILES), 256, 0, stream>>>(h, WT, b2, tiles, perm, wgt, out);
}

// Round 2
// 1034.606 us; speedup vs baseline: 1.0769x; 1.0544x over previous
//
#include <hip/hip_runtime.h>
#include <hip/hip_bf16.h>

#define T_TOKENS 16384
#define DM 1024
#define DFF 4096
#define NEXP 8
#define NT256 72

typedef unsigned short ushort_t;
typedef __attribute__((ext_vector_type(8))) __bf16 bf16x8;
typedef __attribute__((ext_vector_type(4))) float f32x4;

__device__ __forceinline__ void async16(void* lds, const void* g) {
  __builtin_amdgcn_global_load_lds(
      (__attribute__((address_space(1))) void*)(void*)g,
      (__attribute__((address_space(3))) void*)lds, 16, 0, 0);
}

__device__ __forceinline__ ushort_t f2bf(float f) {
  union { float f; unsigned u; } v;
  v.f = f;
  unsigned r = v.u + 0x7FFF + ((v.u >> 16) & 1);
  return (ushort_t)(r >> 16);
}

// ---------------- router: one wave per token ----------------
__global__ __launch_bounds__(256) void router_kernel(
    const float* __restrict__ x, const float* __restrict__ Wr,
    const float* __restrict__ br, int* __restrict__ eidx,
    float* __restrict__ wgt, int* __restrict__ count) {
  int wave = threadIdx.x >> 6;
  int lane = threadIdx.x & 63;
  int t = blockIdx.x * 4 + wave;
  if (t >= T_TOKENS) return;

  float acc[8];
#pragma unroll
  for (int e = 0; e < 8; e++) acc[e] = 0.f;

  const float* xr = x + (size_t)t * DM;
  for (int k = lane; k < DM; k += 64) {
    float xv = xr[k];
    const float4* w4 = (const float4*)(Wr + (size_t)k * 8);
    float4 w0 = w4[0];
    float4 w1 = w4[1];
    acc[0] += xv * w0.x; acc[1] += xv * w0.y;
    acc[2] += xv * w0.z; acc[3] += xv * w0.w;
    acc[4] += xv * w1.x; acc[5] += xv * w1.y;
    acc[6] += xv * w1.z; acc[7] += xv * w1.w;
  }
#pragma unroll
  for (int e = 0; e < 8; e++) {
#pragma unroll
    for (int m = 32; m > 0; m >>= 1) acc[e] += __shfl_xor(acc[e], m, 64);
  }
  if (lane == 0) {
    float lg[8];
    float mx = -1e30f;
#pragma unroll
    for (int e = 0; e < 8; e++) {
      lg[e] = acc[e] + br[e];
      mx = fmaxf(mx, lg[e]);
    }
    float s = 0.f;
#pragma unroll
    for (int e = 0; e < 8; e++) s += expf(lg[e] - mx);
    int am = 0;
    float best = lg[0];
#pragma unroll
    for (int e = 1; e < 8; e++) {
      if (lg[e] > best) { best = lg[e]; am = e; }
    }
    eidx[t] = am;
    wgt[t] = expf(best - mx) / s;
    atomicAdd(&count[am], 1);
  }
}

// ---------------- scan + dense tile table (256-row granularity) ----------------
__global__ void scan_kernel(const int* __restrict__ count, int* __restrict__ offsets,
                            int* __restrict__ cursor, int4* __restrict__ tiles) {
  if (threadIdx.x == 0) {
    int run = 0;
    for (int e = 0; e < NEXP; e++) {
      offsets[e] = run;
      cursor[e] = run;
      run += count[e];
    }
    offsets[NEXP] = run;
    int nt = 0;
    for (int e = 0; e < NEXP; e++) {
      int beg = offsets[e];
      int rows = offsets[e + 1] - beg;
      for (int r0 = 0; r0 < rows; r0 += 256) {
        tiles[nt] = make_int4(e, beg, rows, r0);
        nt++;
      }
    }
    for (; nt < NT256; nt++) tiles[nt] = make_int4(-1, 0, 0, 0);
  }
}

// ---------------- scatter token ids into per-expert lists ----------------
__global__ __launch_bounds__(256) void scatter_kernel(
    const int* __restrict__ eidx, int* __restrict__ cursor, int* __restrict__ perm) {
  int t = blockIdx.x * 256 + threadIdx.x;
  if (t < T_TOKENS) {
    int e = eidx[t];
    int pos = atomicAdd(&cursor[e], 1);
    perm[pos] = t;
  }
}

// ---------------- gather x rows into expert order, fp32 -> bf16 ----------------
__global__ __launch_bounds__(256) void gather_x_kernel(
    const float* __restrict__ x, const int* __restrict__ perm,
    ushort_t* __restrict__ xg) {
  int g = blockIdx.x;
  int tok = perm[g];
  int tid = threadIdx.x;
  float4 v = ((const float4*)(x + (size_t)tok * DM))[tid];
  ushort4 o;
  o.x = f2bf(v.x); o.y = f2bf(v.y); o.z = f2bf(v.z); o.w = f2bf(v.w);
  ((ushort4*)(xg + (size_t)g * DM))[tid] = o;
}

// ---------------- transpose+convert: W [E][R][C] fp32 -> WT [E][C][R] bf16 ----------------
__global__ __launch_bounds__(256) void convT_kernel(
    const float* __restrict__ W, ushort_t* __restrict__ WT, int R, int C) {
  __shared__ float t[64][65];
  int e = blockIdx.z;
  int r0 = blockIdx.y << 6, c0 = blockIdx.x << 6;
  int tid = threadIdx.x;
  const float* Wp = W + (size_t)e * R * C;
#pragma unroll
  for (int i = 0; i < 4; i++) {
    int r = (tid >> 4) + i * 16;
    int c = (tid & 15) * 4;
    float4 v = *(const float4*)(Wp + (size_t)(r0 + r) * C + c0 + c);
    t[r][c] = v.x; t[r][c + 1] = v.y; t[r][c + 2] = v.z; t[r][c + 3] = v.w;
  }
  __syncthreads();
  ushort_t* Op = WT + (size_t)e * R * C;
#pragma unroll
  for (int i = 0; i < 4; i++) {
    int c = (tid >> 4) + i * 16;
    int r = (tid & 15) * 4;
    ushort4 o;
    o.x = f2bf(t[r][c]);
    o.y = f2bf(t[r + 1][c]);
    o.z = f2bf(t[r + 2][c]);
    o.w = f2bf(t[r + 3][c]);
    *(ushort4*)(Op + (size_t)(c0 + c) * R + r0 + r) = o;
  }
}

// ---------------- staging helpers (linear LDS dest, inverse-swizzled global src) ----
// LDS tile layout: [rows][32] elems, 16B chunk kc at (row, kc^((row>>1)&3)).
// 256-row tile: 1024 chunks, 512 threads x 2 issues.
__device__ __forceinline__ void stage256(ushort_t* dst, const ushort_t* src,
                                         int ld, int k0, int tid, int rmax) {
#pragma unroll
  for (int it = 0; it < 2; ++it) {
    int L = it * 512 + tid;
    int row = L >> 2;
    int c = L & 3;
    int gc = c ^ ((row >> 1) & 3);
    int rowc = row > rmax ? rmax : row;
    async16(dst + (size_t)L * 8, src + (size_t)rowc * ld + k0 + gc * 8);
  }
}
// 128-row tile: 512 chunks, 512 threads x 1 issue.
__device__ __forceinline__ void stage128(ushort_t* dst, const ushort_t* src,
                                         int ld, int k0, int tid) {
  int L = tid;
  int row = L >> 2;
  int c = L & 3;
  int gc = c ^ ((row >> 1) & 3);
  async16(dst + (size_t)L * 8, src + (size_t)row * ld + k0 + gc * 8);
}

// bijective XCD-chunk swizzle (m204)
__device__ __forceinline__ int xcd_swizzle(int flat, int nwg) {
  int q = nwg >> 3, r = nwg & 7;
  int xcd = flat & 7, loc = flat >> 3;
  return (xcd < r ? xcd * (q + 1) : r * (q + 1) + (xcd - r) * q) + loc;
}

// ---------------- GEMM1: h = relu(Xg @ W1 + b1). 256x256 tile, 8 waves,
// depth-2 prefetch ring (4 LDS bufs), counted vmcnt, raw barriers. ----------------
__global__ __launch_bounds__(512, 2) void gemm1_kernel(
    const ushort_t* __restrict__ xg, const ushort_t* __restrict__ W1T,
    const float* __restrict__ b1, const int4* __restrict__ tiles,
    ushort_t* __restrict__ h) {
  const int NCOL = DFF / 256;  // 16
  int flat = blockIdx.y * NCOL + blockIdx.x;
  int wgid = xcd_swizzle(flat, NCOL * NT256);
  int ty = wgid / NCOL;
  int cx = wgid - ty * NCOL;

  int4 tl = tiles[ty];
  if (tl.x < 0) return;
  int e = tl.x, beg = tl.y, rows = tl.z, row0 = tl.w;
  int col0 = cx * 256;
  int rmax = rows - row0 - 1;

  __shared__ ushort_t As[4][256 * 32];
  __shared__ ushort_t Bs[4][256 * 32];

  int tid = threadIdx.x;
  int wave = tid >> 6, lane = tid & 63;
  int wm2 = wave >> 2, wn4 = wave & 3;   // 2 (M) x 4 (N) waves
  int lr = lane & 15, kc = lane >> 4;

  int aoff[8], boff[4];
#pragma unroll
  for (int i = 0; i < 8; ++i) {
    int R = wm2 * 128 + i * 16 + lr;
    aoff[i] = R * 32 + ((kc ^ ((R >> 1) & 3)) << 3);
  }
#pragma unroll
  for (int j = 0; j < 4; ++j) {
    int R = wn4 * 64 + j * 16 + lr;
    boff[j] = R * 32 + ((kc ^ ((R >> 1) & 3)) << 3);
  }

  const ushort_t* Ap = xg + (size_t)(beg + row0) * DM;
  const ushort_t* Bp = W1T + ((size_t)e * DFF + col0) * DM;

  f32x4 acc[8][4] = {};

  stage256(As[0], Ap, DM, 0, tid, rmax);
  stage256(Bs[0], Bp, DM, 0, tid, 255);
  stage256(As[1], Ap, DM, 32, tid, rmax);
  stage256(Bs[1], Bp, DM, 32, tid, 255);
  __syncthreads();   // full drain once (prologue only)

  const int KT = DM / 32;  // 32
#pragma unroll 1
  for (int t = 0; t < KT; ++t) {
    const ushort_t* A_ = As[t & 3];
    const ushort_t* B_ = Bs[t & 3];
    bf16x8 bfrag[4], afrag[4];
#pragma unroll
    for (int j = 0; j < 4; ++j) bfrag[j] = *(const bf16x8*)(B_ + boff[j]);
#pragma unroll
    for (int i = 0; i < 4; ++i) afrag[i] = *(const bf16x8*)(A_ + aoff[i]);
    if (t + 2 < KT) stage256(As[(t + 2) & 3], Ap, DM, (t + 2) * 32, tid, rmax);
    __builtin_amdgcn_s_setprio(1);
#pragma unroll
    for (int i = 0; i < 4; ++i)
#pragma unroll
      for (int j = 0; j < 4; ++j)
        acc[i][j] = __builtin_amdgcn_mfma_f32_16x16x32_bf16(afrag[i], bfrag[j], acc[i][j], 0, 0, 0);
    __builtin_amdgcn_s_setprio(0);
#pragma unroll
    for (int i = 0; i < 4; ++i) afrag[i] = *(const bf16x8*)(A_ + aoff[4 + i]);
    if (t + 2 < KT) stage256(Bs[(t + 2) & 3], Bp, DM, (t + 2) * 32, tid, 255);
    __builtin_amdgcn_s_setprio(1);
#pragma unroll
    for (int i = 0; i < 4; ++i)
#pragma unroll
      for (int j = 0; j < 4; ++j)
        acc[4 + i][j] = __builtin_amdgcn_mfma_f32_16x16x32_bf16(afrag[i], bfrag[j], acc[4 + i][j], 0, 0, 0);
    __builtin_amdgcn_s_setprio(0);
    // tile t+1's loads must be landed for ALL waves after the barrier.
    if (t + 2 < KT) {
      asm volatile("s_waitcnt vmcnt(4)" ::: "memory");  // keep tile t+2 in flight
    } else {
      asm volatile("s_waitcnt vmcnt(0)" ::: "memory");  // tail (last 2 tiles)
    }
    __builtin_amdgcn_s_barrier();
    asm volatile("" ::: "memory");  // no LDS read hoists above the barrier
  }

  int rq = (lane >> 4) * 4;
#pragma unroll
  for (int i = 0; i < 8; ++i) {
    int mb = wm2 * 128 + i * 16 + rq;
#pragma unroll
    for (int r = 0; r < 4; ++r) {
      int m = mb + r;
      if (row0 + m < rows) {
        size_t hrow = (size_t)(beg + row0 + m) * DFF;
#pragma unroll
        for (int j = 0; j < 4; ++j) {
          int c = col0 + wn4 * 64 + j * 16 + lr;
          float v = acc[i][j][r] + b1[(size_t)e * DFF + c];
          h[hrow + c] = f2bf(fmaxf(v, 0.f));
        }
      }
    }
  }
}

// ---------------- GEMM2: out = (H @ W2 + b2) * w. 256x128 tile, same pipeline. ----
__global__ __launch_bounds__(512, 2) void gemm2_kernel(
    const ushort_t* __restrict__ h, const ushort_t* __restrict__ W2T,
    const float* __restrict__ b2, const int4* __restrict__ tiles,
    const int* __restrict__ perm, const float* __restrict__ wgt,
    float* __restrict__ out) {
  const int NCOL = DM / 128;  // 8
  int flat = blockIdx.y * NCOL + blockIdx.x;
  int wgid = xcd_swizzle(flat, NCOL * NT256);
  int ty = wgid / NCOL;
  int cx = wgid - ty * NCOL;

  int4 tl = tiles[ty];
  if (tl.x < 0) return;
  int e = tl.x, beg = tl.y, rows = tl.z, row0 = tl.w;
  int col0 = cx * 128;
  int rmax = rows - row0 - 1;

  __shared__ ushort_t As[4][256 * 32];
  __shared__ ushort_t Bs[4][128 * 32];
  __shared__ int toks[256];

  int tid = threadIdx.x;
  if (tid < 256) {
    int r = row0 + tid;
    toks[tid] = (r < rows) ? perm[beg + r] : 0;
  }

  int wave = tid >> 6, lane = tid & 63;
  int wm2 = wave >> 2, wn4 = wave & 3;
  int lr = lane & 15, kc = lane >> 4;

  int aoff[8], boff[2];
#pragma unroll
  for (int i = 0; i < 8; ++i) {
    int R = wm2 * 128 + i * 16 + lr;
    aoff[i] = R * 32 + ((kc ^ ((R >> 1) & 3)) << 3);
  }
#pragma unroll
  for (int j = 0; j < 2; ++j) {
    int R = wn4 * 32 + j * 16 + lr;
    boff[j] = R * 32 + ((kc ^ ((R >> 1) & 3)) << 3);
  }

  const ushort_t* Ap = h + (size_t)(beg + row0) * DFF;
  const ushort_t* Bp = W2T + ((size_t)e * DM + col0) * DFF;

  f32x4 acc[8][2] = {};

  stage256(As[0], Ap, DFF, 0, tid, rmax);
  stage128(Bs[0], Bp, DFF, 0, tid);
  stage256(As[1], Ap, DFF, 32, tid, rmax);
  stage128(Bs[1], Bp, DFF, 32, tid);
  __syncthreads();

  const int KT = DFF / 32;  // 128
#pragma unroll 1
  for (int t = 0; t < KT; ++t) {
    const ushort_t* A_ = As[t & 3];
    const ushort_t* B_ = Bs[t & 3];
    bf16x8 bfrag[2], afrag[4];
#pragma unroll
    for (int j = 0; j < 2; ++j) bfrag[j] = *(const bf16x8*)(B_ + boff[j]);
#pragma unroll
    for (int i = 0; i < 4; ++i) afrag[i] = *(const bf16x8*)(A_ + aoff[i]);
    if (t + 2 < KT) stage256(As[(t + 2) & 3], Ap, DFF, (t + 2) * 32, tid, rmax);
    __builtin_amdgcn_s_setprio(1);
#pragma unroll
    for (int i = 0; i < 4; ++i)
#pragma unroll
      for (int j = 0; j < 2; ++j)
        acc[i][j] = __builtin_amdgcn_mfma_f32_16x16x32_bf16(afrag[i], bfrag[j], acc[i][j], 0, 0, 0);
    __builtin_amdgcn_s_setprio(0);
#pragma unroll
    for (int i = 0; i < 4; ++i) afrag[i] = *(const bf16x8*)(A_ + aoff[4 + i]);
    if (t + 2 < KT) stage128(Bs[(t + 2) & 3], Bp, DFF, (t + 2) * 32, tid);
    __builtin_amdgcn_s_setprio(1);
#pragma unroll
    for (int i = 0; i < 4; ++i)
#pragma unroll
      for (int j = 0; j < 2; ++j)
        acc[4 + i][j] = __builtin_amdgcn_mfma_f32_16x16x32_bf16(afrag[i], bfrag[j], acc[4 + i][j], 0, 0, 0);
    __builtin_amdgcn_s_setprio(0);
    if (t + 2 < KT) {
      asm volatile("s_waitcnt vmcnt(3)" ::: "memory");  // 3 loads/tile in flight
    } else {
      asm volatile("s_waitcnt vmcnt(0)" ::: "memory");
    }
    __builtin_amdgcn_s_barrier();
    asm volatile("" ::: "memory");
  }

  int rq = (lane >> 4) * 4;
#pragma unroll
  for (int i = 0; i < 8; ++i) {
    int mb = wm2 * 128 + i * 16 + rq;
#pragma unroll
    for (int r = 0; r < 4; ++r) {
      int m = mb + r;
      if (row0 + m < rows) {
        int tok = toks[m];
        float* orow = out + (size_t)tok * DM;
        float w = wgt[tok];
#pragma unroll
        for (int j = 0; j < 2; ++j) {
          int c = col0 + wn4 * 32 + j * 16 + lr;
          orow[c] = (acc[i][j][r] + b2[(size_t)e * DM + c]) * w;
        }
      }
    }
  }
}

extern "C" void kernel_launch(void* const* d_in, const int* in_sizes, int n_in,
                              void* d_out, int out_size, void* d_ws, size_t ws_size,
                              hipStream_t stream) {
  (void)in_sizes; (void)n_in; (void)out_size; (void)ws_size;
  const float* x  = (const float*)d_in[0];
  const float* Wr = (const float*)d_in[1];
  const float* br = (const float*)d_in[2];
  const float* W1 = (const float*)d_in[3];
  const float* b1 = (const float*)d_in[4];
  const float* W2 = (const float*)d_in[5];
  const float* b2 = (const float*)d_in[6];
  float* out = (float*)d_out;

  char* ws = (char*)d_ws;
  int*   eidx    = (int*)(ws + 0);
  float* wgt     = (float*)(ws + 65536);
  int*   count   = (int*)(ws + 131072);
  int*   offsets = (int*)(ws + 131136);
  int*   cursor  = (int*)(ws + 131264);
  int4*  tiles   = (int4*)(ws + 131392);
  int*   perm    = (int*)(ws + 135168);

  size_t XG_BYTES = (size_t)T_TOKENS * DM * sizeof(ushort_t);   // 32 MB
  ushort_t* xg = (ushort_t*)(ws + 262144);
  ushort_t* WT = (ushort_t*)(ws + 262144 + XG_BYTES);           // shared W1T/W2T, 64 MB
  ushort_t* h  = (ushort_t*)(ws + 262144 + XG_BYTES + 67108864);
  // watermark: 0.25 + 32 + 64 + 128 MB = 235.1 MB (ws proven >= 303.5 MB)

  hipMemsetAsync(count, 0, 32, stream);

  router_kernel<<<T_TOKENS / 4, 256, 0, stream>>>(x, Wr, br, eidx, wgt, count);
  scan_kernel<<<1, 64, 0, stream>>>(count, offsets, cursor, tiles);
  scatter_kernel<<<T_TOKENS / 256, 256, 0, stream>>>(eidx, cursor, perm);
  gather_x_kernel<<<T_TOKENS, 256, 0, stream>>>(x, perm, xg);

  convT_kernel<<<dim3(DFF / 64, DM / 64, NEXP), 256, 0, stream>>>(W1, WT, DM, DFF);
  gemm1_kernel<<<dim3(DFF / 256, NT256), 512, 0, stream>>>(xg, WT, b1, tiles, h);

  convT_kernel<<<dim3(DM / 64, DFF / 64, NEXP), 256, 0, stream>>>(W2, WT, DFF, DM);
  gemm2_kernel<<<dim3(DM / 128, NT256), 512, 0, stream>>>(h, WT, b2, tiles, perm, wgt, out);
}

// Round 3
// 796.981 us; speedup vs baseline: 1.3980x; 1.2982x over previous
//
#include <hip/hip_runtime.h>
#include <hip/hip_bf16.h>

#define T_TOKENS 16384
#define DM 1024
#define DFF 4096
#define NEXP 8
#define NTILES 136

typedef unsigned short ushort_t;
typedef __attribute__((ext_vector_type(8))) __bf16 bf16x8;
typedef __attribute__((ext_vector_type(4))) float f32x4;

__device__ __forceinline__ void async16(void* lds, const void* g) {
  __builtin_amdgcn_global_load_lds(
      (__attribute__((address_space(1))) void*)(void*)g,
      (__attribute__((address_space(3))) void*)lds, 16, 0, 0);
}

__device__ __forceinline__ ushort_t f2bf(float f) {
  union { float f; unsigned u; } v;
  v.f = f;
  unsigned r = v.u + 0x7FFF + ((v.u >> 16) & 1);
  return (ushort_t)(r >> 16);
}

// ---------------- router: one wave per token, NO atomics ----------------
__global__ __launch_bounds__(256) void router_kernel(
    const float* __restrict__ x, const float* __restrict__ Wr,
    const float* __restrict__ br, int* __restrict__ eidx,
    float* __restrict__ wgt) {
  int wave = threadIdx.x >> 6;
  int lane = threadIdx.x & 63;
  int t = blockIdx.x * 4 + wave;
  if (t >= T_TOKENS) return;

  float acc[8];
#pragma unroll
  for (int e = 0; e < 8; e++) acc[e] = 0.f;

  const float* xr = x + (size_t)t * DM;
  for (int k = lane; k < DM; k += 64) {
    float xv = xr[k];
    const float4* w4 = (const float4*)(Wr + (size_t)k * 8);
    float4 w0 = w4[0];
    float4 w1 = w4[1];
    acc[0] += xv * w0.x; acc[1] += xv * w0.y;
    acc[2] += xv * w0.z; acc[3] += xv * w0.w;
    acc[4] += xv * w1.x; acc[5] += xv * w1.y;
    acc[6] += xv * w1.z; acc[7] += xv * w1.w;
  }
#pragma unroll
  for (int e = 0; e < 8; e++) {
#pragma unroll
    for (int m = 32; m > 0; m >>= 1) acc[e] += __shfl_xor(acc[e], m, 64);
  }
  if (lane == 0) {
    float lg[8];
    float mx = -1e30f;
#pragma unroll
    for (int e = 0; e < 8; e++) {
      lg[e] = acc[e] + br[e];
      mx = fmaxf(mx, lg[e]);
    }
    float s = 0.f;
#pragma unroll
    for (int e = 0; e < 8; e++) s += expf(lg[e] - mx);
    int am = 0;
    float best = lg[0];
#pragma unroll
    for (int e = 1; e < 8; e++) {
      if (lg[e] > best) { best = lg[e]; am = e; }
    }
    eidx[t] = am;
    wgt[t] = expf(best - mx) / s;
  }
}

// ---------------- hist + scan + tile table, one block, ballot-based ----------------
__global__ __launch_bounds__(1024) void hist_scan_kernel(
    const int* __restrict__ eidx, int* __restrict__ offsets,
    int* __restrict__ cursor, int4* __restrict__ tiles) {
  __shared__ int wcnt[16][8];
  int wave = threadIdx.x >> 6, lane = threadIdx.x & 63;
  int c[8];
#pragma unroll
  for (int q = 0; q < 8; ++q) c[q] = 0;
  for (int i = 0; i < 16; ++i) {
    int e = eidx[i * 1024 + threadIdx.x];
#pragma unroll
    for (int q = 0; q < 8; ++q)
      c[q] += (int)__popcll(__ballot(e == q));
  }
  if (lane == 0) {
#pragma unroll
    for (int q = 0; q < 8; ++q) wcnt[wave][q] = c[q];
  }
  __syncthreads();
  if (threadIdx.x == 0) {
    int off[NEXP + 1];
    int run = 0;
    for (int e = 0; e < NEXP; ++e) {
      int tot = 0;
      for (int w = 0; w < 16; ++w) tot += wcnt[w][e];
      off[e] = run;
      offsets[e] = run;
      cursor[e] = run;
      run += tot;
    }
    off[NEXP] = run;
    offsets[NEXP] = run;
    int nt = 0;
    for (int e = 0; e < NEXP; ++e) {
      int beg = off[e];
      int rows = off[e + 1] - beg;
      for (int r0 = 0; r0 < rows; r0 += 128) {
        tiles[nt] = make_int4(e, beg, rows, r0);
        nt++;
      }
    }
    for (; nt < NTILES; nt++) tiles[nt] = make_int4(-1, 0, 0, 0);
  }
}

// ---------------- scatter: block-chunked, 8 global atomics per block ----------------
__global__ __launch_bounds__(256) void scatter_kernel(
    const int* __restrict__ eidx, int* __restrict__ cursor, int* __restrict__ perm) {
  __shared__ int wcnt[4][8];
  __shared__ int woff[4][8];
  __shared__ int base[8];
  int tid = threadIdx.x;
  int wave = tid >> 6, lane = tid & 63;
  int t = blockIdx.x * 256 + tid;
  int e = eidx[t];
  unsigned long long lt = (1ull << lane) - 1ull;
  int myrank = 0;
#pragma unroll
  for (int q = 0; q < 8; ++q) {
    unsigned long long b = __ballot(e == q);
    if (e == q) myrank = (int)__popcll(b & lt);
    if (lane == 0) wcnt[wave][q] = (int)__popcll(b);
  }
  __syncthreads();
  if (tid < 8) {
    int run = 0;
    for (int w = 0; w < 4; ++w) { woff[w][tid] = run; run += wcnt[w][tid]; }
    base[tid] = atomicAdd(&cursor[tid], run);
  }
  __syncthreads();
  perm[base[e] + woff[wave][e] + myrank] = t;
}

// ---------------- gather x rows into expert order, fp32 -> bf16 ----------------
__global__ __launch_bounds__(256) void gather_x_kernel(
    const float* __restrict__ x, const int* __restrict__ perm,
    ushort_t* __restrict__ xg) {
  int g = blockIdx.x;
  int tok = perm[g];
  int tid = threadIdx.x;
  float4 v = ((const float4*)(x + (size_t)tok * DM))[tid];
  ushort4 o;
  o.x = f2bf(v.x); o.y = f2bf(v.y); o.z = f2bf(v.z); o.w = f2bf(v.w);
  ((ushort4*)(xg + (size_t)g * DM))[tid] = o;
}

// ---------------- transpose+convert BOTH weights in one launch ----------------
// z<8: W1 expert z (R=DM,C=DFF); z>=8: W2 expert z-8 (R=DFF,C=DM).
__global__ __launch_bounds__(256) void convT_all_kernel(
    const float* __restrict__ W1, const float* __restrict__ W2,
    ushort_t* __restrict__ W1T, ushort_t* __restrict__ W2T) {
  __shared__ float t[64][65];
  int z = blockIdx.y;
  const float* Wp;
  ushort_t* Op;
  int R, C, bx, by;
  if (z < 8) {
    Wp = W1 + (size_t)z * DM * DFF;
    Op = W1T + (size_t)z * DM * DFF;
    R = DM; C = DFF;
    bx = blockIdx.x & 63; by = blockIdx.x >> 6;   // 64 x 16
  } else {
    Wp = W2 + (size_t)(z - 8) * DFF * DM;
    Op = W2T + (size_t)(z - 8) * DFF * DM;
    R = DFF; C = DM;
    bx = blockIdx.x & 15; by = blockIdx.x >> 4;   // 16 x 64
  }
  int r0 = by << 6, c0 = bx << 6;
  int tid = threadIdx.x;
#pragma unroll
  for (int i = 0; i < 4; i++) {
    int r = (tid >> 4) + i * 16;
    int c = (tid & 15) * 4;
    float4 v = *(const float4*)(Wp + (size_t)(r0 + r) * C + c0 + c);
    t[r][c] = v.x; t[r][c + 1] = v.y; t[r][c + 2] = v.z; t[r][c + 3] = v.w;
  }
  __syncthreads();
#pragma unroll
  for (int i = 0; i < 4; i++) {
    int c = (tid >> 4) + i * 16;
    int r = (tid & 15) * 4;
    ushort4 o;
    o.x = f2bf(t[r][c]);
    o.y = f2bf(t[r + 1][c]);
    o.z = f2bf(t[r + 2][c]);
    o.w = f2bf(t[r + 3][c]);
    *(ushort4*)(Op + (size_t)(c0 + c) * R + r0 + r) = o;
  }
}

// ---------------- staging: linear LDS dest, inverse-swizzled global src ----------
// LDS tile [128 rows][32 elems]; 16B chunk kc of row R at slot kc^((R>>1)&3).
__device__ __forceinline__ void stage128(ushort_t* dst, const ushort_t* src,
                                         int ld, int k0, int tid, int rmax) {
  int row = tid >> 2;
  int c = tid & 3;
  int gc = c ^ ((row >> 1) & 3);
  int rowc = row > rmax ? rmax : row;
  async16(dst + (size_t)tid * 8, src + (size_t)rowc * ld + k0 + gc * 8);
}

// bijective XCD-chunk swizzle (m204)
__device__ __forceinline__ int xcd_swizzle(int flat, int nwg) {
  int q = nwg >> 3, r = nwg & 7;
  int xcd = flat & 7, loc = flat >> 3;
  return (xcd < r ? xcd * (q + 1) : r * (q + 1) + (xcd - r) * q) + loc;
}

// ---------------- GEMM1: h = relu(Xg @ W1 + b1). 128x128 tile, 8 waves,
// ring-3 LDS (48KB -> 2 blocks/CU), depth-2 prefetch, counted vmcnt. -------------
__global__ __launch_bounds__(512, 2) void gemm1_kernel(
    const ushort_t* __restrict__ xg, const ushort_t* __restrict__ W1T,
    const float* __restrict__ b1, const int4* __restrict__ tiles,
    ushort_t* __restrict__ h) {
  const int NCOL = DFF / 128;  // 32
  int flat = blockIdx.y * NCOL + blockIdx.x;
  int wgid = xcd_swizzle(flat, NCOL * NTILES);
  int ty = wgid / NCOL;
  int cx = wgid - ty * NCOL;

  int4 tl = tiles[ty];
  if (tl.x < 0) return;
  int e = tl.x, beg = tl.y, rows = tl.z, row0 = tl.w;
  int col0 = cx * 128;
  int rmax = rows - row0 - 1;

  __shared__ ushort_t As[3][128 * 32];
  __shared__ ushort_t Bs[3][128 * 32];

  int tid = threadIdx.x;
  int wave = tid >> 6, lane = tid & 63;
  int wm2 = wave >> 2, wn4 = wave & 3;  // 2 (M) x 4 (N)
  int lr = lane & 15, kc = lane >> 4;

  int aoff[4], boff[2];
#pragma unroll
  for (int i = 0; i < 4; ++i) {
    int R = wm2 * 64 + i * 16 + lr;
    aoff[i] = R * 32 + ((kc ^ ((R >> 1) & 3)) << 3);
  }
#pragma unroll
  for (int j = 0; j < 2; ++j) {
    int R = wn4 * 32 + j * 16 + lr;
    boff[j] = R * 32 + ((kc ^ ((R >> 1) & 3)) << 3);
  }

  const ushort_t* Ap = xg + (size_t)(beg + row0) * DM;
  const ushort_t* Bp = W1T + ((size_t)e * DFF + col0) * DM;

  f32x4 acc[4][2] = {};

  stage128(As[0], Ap, DM, 0, tid, rmax);
  stage128(Bs[0], Bp, DM, 0, tid, 127);
  stage128(As[1], Ap, DM, 32, tid, rmax);
  stage128(Bs[1], Bp, DM, 32, tid, 127);
  __syncthreads();  // full drain (prologue only)

  const int KT = DM / 32;  // 32
  int cur = 0;
#pragma unroll 1
  for (int t = 0; t < KT; ++t) {
    const ushort_t* A_ = As[cur];
    const ushort_t* B_ = Bs[cur];
    int nx2 = cur + 2; if (nx2 >= 3) nx2 -= 3;
    bf16x8 afr[4], bfr[2];
#pragma unroll
    for (int j = 0; j < 2; ++j) bfr[j] = *(const bf16x8*)(B_ + boff[j]);
#pragma unroll
    for (int i = 0; i < 4; ++i) afr[i] = *(const bf16x8*)(A_ + aoff[i]);
    if (t + 2 < KT) {
      stage128(As[nx2], Ap, DM, (t + 2) * 32, tid, rmax);
      stage128(Bs[nx2], Bp, DM, (t + 2) * 32, tid, 127);
    }
    __builtin_amdgcn_s_setprio(1);
#pragma unroll
    for (int i = 0; i < 4; ++i)
#pragma unroll
      for (int j = 0; j < 2; ++j)
        acc[i][j] = __builtin_amdgcn_mfma_f32_16x16x32_bf16(afr[i], bfr[j], acc[i][j], 0, 0, 0);
    __builtin_amdgcn_s_setprio(0);
    if (t + 2 < KT) {
      asm volatile("s_waitcnt vmcnt(2)" ::: "memory");  // tile t+1 landed, t+2 in flight
    } else {
      asm volatile("s_waitcnt vmcnt(0)" ::: "memory");
    }
    __builtin_amdgcn_s_barrier();
    asm volatile("" ::: "memory");
    cur = (cur + 1 == 3) ? 0 : cur + 1;
  }

  int rq = (lane >> 4) * 4;
#pragma unroll
  for (int i = 0; i < 4; ++i) {
    int mb = wm2 * 64 + i * 16 + rq;
#pragma unroll
    for (int r = 0; r < 4; ++r) {
      int m = mb + r;
      if (row0 + m < rows) {
        size_t hrow = (size_t)(beg + row0 + m) * DFF;
#pragma unroll
        for (int j = 0; j < 2; ++j) {
          int c = col0 + wn4 * 32 + j * 16 + lr;
          float v = acc[i][j][r] + b1[(size_t)e * DFF + c];
          h[hrow + c] = f2bf(fmaxf(v, 0.f));
        }
      }
    }
  }
}

// ---------------- GEMM2: out = (H @ W2 + b2) * w. Same structure, K=DFF. --------
__global__ __launch_bounds__(512, 2) void gemm2_kernel(
    const ushort_t* __restrict__ h, const ushort_t* __restrict__ W2T,
    const float* __restrict__ b2, const int4* __restrict__ tiles,
    const int* __restrict__ perm, const float* __restrict__ wgt,
    float* __restrict__ out) {
  const int NCOL = DM / 128;  // 8
  int flat = blockIdx.y * NCOL + blockIdx.x;
  int wgid = xcd_swizzle(flat, NCOL * NTILES);
  int ty = wgid / NCOL;
  int cx = wgid - ty * NCOL;

  int4 tl = tiles[ty];
  if (tl.x < 0) return;
  int e = tl.x, beg = tl.y, rows = tl.z, row0 = tl.w;
  int col0 = cx * 128;
  int rmax = rows - row0 - 1;

  __shared__ ushort_t As[3][128 * 32];
  __shared__ ushort_t Bs[3][128 * 32];
  __shared__ int toks[128];

  int tid = threadIdx.x;
  if (tid < 128) {
    int r = row0 + tid;
    toks[tid] = (r < rows) ? perm[beg + r] : 0;
  }

  int wave = tid >> 6, lane = tid & 63;
  int wm2 = wave >> 2, wn4 = wave & 3;
  int lr = lane & 15, kc = lane >> 4;

  int aoff[4], boff[2];
#pragma unroll
  for (int i = 0; i < 4; ++i) {
    int R = wm2 * 64 + i * 16 + lr;
    aoff[i] = R * 32 + ((kc ^ ((R >> 1) & 3)) << 3);
  }
#pragma unroll
  for (int j = 0; j < 2; ++j) {
    int R = wn4 * 32 + j * 16 + lr;
    boff[j] = R * 32 + ((kc ^ ((R >> 1) & 3)) << 3);
  }

  const ushort_t* Ap = h + (size_t)(beg + row0) * DFF;
  const ushort_t* Bp = W2T + ((size_t)e * DM + col0) * DFF;

  f32x4 acc[4][2] = {};

  stage128(As[0], Ap, DFF, 0, tid, rmax);
  stage128(Bs[0], Bp, DFF, 0, tid, 127);
  stage128(As[1], Ap, DFF, 32, tid, rmax);
  stage128(Bs[1], Bp, DFF, 32, tid, 127);
  __syncthreads();

  const int KT = DFF / 32;  // 128
  int cur = 0;
#pragma unroll 1
  for (int t = 0; t < KT; ++t) {
    const ushort_t* A_ = As[cur];
    const ushort_t* B_ = Bs[cur];
    int nx2 = cur + 2; if (nx2 >= 3) nx2 -= 3;
    bf16x8 afr[4], bfr[2];
#pragma unroll
    for (int j = 0; j < 2; ++j) bfr[j] = *(const bf16x8*)(B_ + boff[j]);
#pragma unroll
    for (int i = 0; i < 4; ++i) afr[i] = *(const bf16x8*)(A_ + aoff[i]);
    if (t + 2 < KT) {
      stage128(As[nx2], Ap, DFF, (t + 2) * 32, tid, rmax);
      stage128(Bs[nx2], Bp, DFF, (t + 2) * 32, tid, 127);
    }
    __builtin_amdgcn_s_setprio(1);
#pragma unroll
    for (int i = 0; i < 4; ++i)
#pragma unroll
      for (int j = 0; j < 2; ++j)
        acc[i][j] = __builtin_amdgcn_mfma_f32_16x16x32_bf16(afr[i], bfr[j], acc[i][j], 0, 0, 0);
    __builtin_amdgcn_s_setprio(0);
    if (t + 2 < KT) {
      asm volatile("s_waitcnt vmcnt(2)" ::: "memory");
    } else {
      asm volatile("s_waitcnt vmcnt(0)" ::: "memory");
    }
    __builtin_amdgcn_s_barrier();
    asm volatile("" ::: "memory");
    cur = (cur + 1 == 3) ? 0 : cur + 1;
  }

  int rq = (lane >> 4) * 4;
#pragma unroll
  for (int i = 0; i < 4; ++i) {
    int mb = wm2 * 64 + i * 16 + rq;
#pragma unroll
    for (int r = 0; r < 4; ++r) {
      int m = mb + r;
      if (row0 + m < rows) {
        int tok = toks[m];
        float* orow = out + (size_t)tok * DM;
        float w = wgt[tok];
#pragma unroll
        for (int j = 0; j < 2; ++j) {
          int c = col0 + wn4 * 32 + j * 16 + lr;
          orow[c] = (acc[i][j][r] + b2[(size_t)e * DM + c]) * w;
        }
      }
    }
  }
}

extern "C" void kernel_launch(void* const* d_in, const int* in_sizes, int n_in,
                              void* d_out, int out_size, void* d_ws, size_t ws_size,
                              hipStream_t stream) {
  (void)in_sizes; (void)n_in; (void)out_size; (void)ws_size;
  const float* x  = (const float*)d_in[0];
  const float* Wr = (const float*)d_in[1];
  const float* br = (const float*)d_in[2];
  const float* W1 = (const float*)d_in[3];
  const float* b1 = (const float*)d_in[4];
  const float* W2 = (const float*)d_in[5];
  const float* b2 = (const float*)d_in[6];
  float* out = (float*)d_out;

  char* ws = (char*)d_ws;
  int*   eidx    = (int*)(ws + 0);          // 64 KB
  float* wgt     = (float*)(ws + 65536);    // 64 KB
  int*   offsets = (int*)(ws + 131072);     // 9 ints
  int*   cursor  = (int*)(ws + 131136);     // 8 ints
  int4*  tiles   = (int4*)(ws + 131200);    // 136 * 16 B (16-aligned)
  int*   perm    = (int*)(ws + 133376);     // 64 KB

  // xg 32MB + W1T 64MB + W2T 64MB + h 128MB -> total 302,252,032 B
  // (< 303,562,752 B proven-available watermark from round 0)
  ushort_t* xg  = (ushort_t*)(ws + 262144);
  ushort_t* W1T = (ushort_t*)(ws + 262144 + 33554432ull);
  ushort_t* W2T = (ushort_t*)(ws + 262144 + 33554432ull + 67108864ull);
  ushort_t* h   = (ushort_t*)(ws + 262144 + 33554432ull + 134217728ull);

  router_kernel<<<T_TOKENS / 4, 256, 0, stream>>>(x, Wr, br, eidx, wgt);
  hist_scan_kernel<<<1, 1024, 0, stream>>>(eidx, offsets, cursor, tiles);
  scatter_kernel<<<T_TOKENS / 256, 256, 0, stream>>>(eidx, cursor, perm);
  gather_x_kernel<<<T_TOKENS, 256, 0, stream>>>(x, perm, xg);
  convT_all_kernel<<<dim3(1024, 16), 256, 0, stream>>>(W1, W2, W1T, W2T);

  gemm1_kernel<<<dim3(DFF / 128, NTILES), 512, 0, stream>>>(xg, W1T, b1, tiles, h);
  gemm2_kernel<<<dim3(DM / 128, NTILES), 512, 0, stream>>>(h, W2T, b2, tiles, perm, wgt, out);
}